// Round 5
// baseline (2165.869 us; speedup 1.0000x reference)
//
#include <hip/hip_runtime.h>
#include <hip/hip_bf16.h>
#include <math.h>

// V=32000 E=512 H=1024 A=1024 L=2 B=16 T=64 S=64
typedef __bf16 bf16x8 __attribute__((ext_vector_type(8)));
typedef float  f32x4  __attribute__((ext_vector_type(4)));

#define MFMA16 __builtin_amdgcn_mfma_f32_16x16x32_bf16

__device__ __forceinline__ float sigm(float x){ return 1.0f/(1.0f+expf(-x)); }
__device__ __forceinline__ f32x4 ld4(const float* p){ return *(const f32x4*)p; }
__device__ __forceinline__ void split2(float x, __bf16* h, __bf16* l){
  __bf16 hh = (__bf16)x; *h = hh; *l = (__bf16)(x - (float)hh);
}

// ---------- transpose fp32 ----------
__global__ __launch_bounds__(256) void k_transpose(const float* __restrict__ in,
                                                   float* __restrict__ out, int R, int C){
  __shared__ float tile[32][33];
  int c0 = blockIdx.x*32, r0 = blockIdx.y*32;
  int tx = threadIdx.x & 31, ty = threadIdx.x >> 5;
  for(int i=ty;i<32;i+=8) tile[i][tx] = in[(size_t)(r0+i)*C + c0+tx];
  __syncthreads();
  for(int i=ty;i<32;i+=8) out[(size_t)(c0+i)*R + r0+tx] = tile[tx][i];
}

// ---------- gather fp32 ----------
__global__ __launch_bounds__(256) void k_gather(const int* __restrict__ tgt,
                                                const float* __restrict__ emb,
                                                float* __restrict__ emb_tok){
  int m = blockIdx.x;            // m = t*16+b
  int t = m >> 4, b = m & 15;
  int row = tgt[b*64 + t];
  const float* src = emb + (size_t)row*512;
  float* dst = emb_tok + (size_t)m*512;
  for(int e=threadIdx.x;e<512;e+=256) dst[e] = src[e];
}

// ---------- setup GEMM: C[m][n] = sum_k A[m][k]*Bt[n][k] + bias[n] (hi/lo MFMA) ----------
__global__ __launch_bounds__(256) void k_gemm_s(
    const float* __restrict__ A, int lda,
    const float* __restrict__ Bt, int ldb,
    const float* __restrict__ bias,
    float* __restrict__ C, int N, int K)
{
  __shared__ __align__(16) __bf16 Ash[128][40];
  __shared__ __align__(16) __bf16 Asl[128][40];
  __shared__ __align__(16) __bf16 Bsh[64][40];
  __shared__ __align__(16) __bf16 Bsl[64][40];
  int tid = threadIdx.x;
  int m0 = blockIdx.x*128, n0 = blockIdx.y*64;
  int lane = tid & 63, wave = tid >> 6;
  int wr = wave >> 1, wc = wave & 1;
  int qq = lane >> 4, rr = lane & 15;
  f32x4 acc[4][2] = {};
  int ar = tid >> 1, ak = (tid & 1)*16;
  int br = tid >> 2, bk = (tid & 3)*8;
  for(int k0=0;k0<K;k0+=32){
    const float* ap = A + (size_t)(m0+ar)*lda + k0 + ak;
    f32x4 a0 = ld4(ap), a1 = ld4(ap+4), a2 = ld4(ap+8), a3 = ld4(ap+12);
    const float* bp = Bt + (size_t)(n0+br)*ldb + k0 + bk;
    f32x4 b0 = ld4(bp), b1 = ld4(bp+4);
    __syncthreads();
    #pragma unroll
    for(int e=0;e<4;++e){
      split2(a0[e], &Ash[ar][ak+e],    &Asl[ar][ak+e]);
      split2(a1[e], &Ash[ar][ak+4+e],  &Asl[ar][ak+4+e]);
      split2(a2[e], &Ash[ar][ak+8+e],  &Asl[ar][ak+8+e]);
      split2(a3[e], &Ash[ar][ak+12+e], &Asl[ar][ak+12+e]);
      split2(b0[e], &Bsh[br][bk+e],    &Bsl[br][bk+e]);
      split2(b1[e], &Bsh[br][bk+4+e],  &Bsl[br][bk+4+e]);
    }
    __syncthreads();
    bf16x8 afh[4], afl[4], bfh[2], bfl[2];
    #pragma unroll
    for(int mi=0;mi<4;++mi){
      afh[mi] = *(const bf16x8*)&Ash[wr*64 + mi*16 + rr][qq*8];
      afl[mi] = *(const bf16x8*)&Asl[wr*64 + mi*16 + rr][qq*8];
    }
    #pragma unroll
    for(int ni=0;ni<2;++ni){
      bfh[ni] = *(const bf16x8*)&Bsh[wc*32 + ni*16 + rr][qq*8];
      bfl[ni] = *(const bf16x8*)&Bsl[wc*32 + ni*16 + rr][qq*8];
    }
    #pragma unroll
    for(int mi=0;mi<4;++mi)
      #pragma unroll
      for(int ni=0;ni<2;++ni){
        acc[mi][ni] = MFMA16(afh[mi], bfh[ni], acc[mi][ni], 0,0,0);
        acc[mi][ni] = MFMA16(afl[mi], bfh[ni], acc[mi][ni], 0,0,0);
        acc[mi][ni] = MFMA16(afh[mi], bfl[ni], acc[mi][ni], 0,0,0);
      }
  }
  #pragma unroll
  for(int mi=0;mi<4;++mi)
    #pragma unroll
    for(int ni=0;ni<2;++ni)
      #pragma unroll
      for(int i=0;i<4;++i){
        int m = m0 + wr*64 + mi*16 + qq*4 + i;
        int n = n0 + wc*32 + ni*16 + rr;
        C[(size_t)m*N + n] = acc[mi][ni][i] + (bias? bias[n] : 0.f);
      }
}

// ---------- pack W[J][1024] fp32 -> MFMA B-frag panels, bf16 hi/lo ----------
__global__ __launch_bounds__(256) void k_pack_w(const float* __restrict__ W,
                                                __bf16* __restrict__ Wp){
  int jt = blockIdx.x, tid = threadIdx.x;
  #pragma unroll
  for(int it=0; it<8; ++it){
    int pos = it*256 + tid;           // 0..2047
    int kt = pos>>6, l = pos&63;
    const float* src = W + (size_t)(jt*16 + (l&15))*1024 + kt*32 + (l>>4)*8;
    f32x4 s0 = ld4(src), s1 = ld4(src+4);
    bf16x8 vh, vl;
    #pragma unroll
    for(int e=0;e<4;++e){
      __bf16 h, lo;
      split2(s0[e], &h, &lo); vh[e]   = h; vl[e]   = lo;
      split2(s1[e], &h, &lo); vh[4+e] = h; vl[4+e] = lo;
    }
    __bf16* dst = Wp + ((size_t)(jt*32 + kt))*1024 + l*8;
    *(bf16x8*)dst       = vh;
    *(bf16x8*)(dst+512) = vl;
  }
}

// ---------- pack, reading W transposed: value[j][k] = W[k][j] (ldw cols) ----------
__global__ __launch_bounds__(256) void k_pack_wT(const float* __restrict__ W, int ldw,
                                                 __bf16* __restrict__ Wp){
  int jt = blockIdx.x, tid = threadIdx.x;
  #pragma unroll
  for(int it=0; it<8; ++it){
    int pos = it*256 + tid;
    int kt = pos>>6, l = pos&63;
    int j = jt*16 + (l&15);
    int kbase = kt*32 + (l>>4)*8;
    bf16x8 vh, vl;
    #pragma unroll
    for(int e=0;e<8;++e){
      float x = W[(size_t)(kbase+e)*ldw + j];
      __bf16 h = (__bf16)x;
      vh[e] = h; vl[e] = (__bf16)(x - (float)h);
    }
    __bf16* dst = Wp + ((size_t)(jt*32 + kt))*1024 + l*8;
    *(bf16x8*)dst       = vh;
    *(bf16x8*)(dst+512) = vl;
  }
}

// ---------- split hidden -> h0/h1 bf16 hi/lo ----------
__global__ __launch_bounds__(256) void k_split_h(const float* __restrict__ hidden,
    __bf16* __restrict__ h0h, __bf16* __restrict__ h0l,
    __bf16* __restrict__ h1h, __bf16* __restrict__ h1l){
  int i = blockIdx.x*256 + threadIdx.x;
  float x = hidden[i];
  if(i < 16384) split2(x, &h0h[i], &h0l[i]);
  else { int j = i - 16384; split2(x, &h1h[j], &h1l[j]); }
}

// ---------- fp32 -> bf16 (x8 vectorized) ----------
__global__ __launch_bounds__(256) void k_cvt16(const float* __restrict__ in,
                                               __bf16* __restrict__ out){
  int i = blockIdx.x*256 + threadIdx.x;
  const float* p = in + (size_t)i*8;
  f32x4 f0 = ld4(p), f1 = ld4(p+4);
  bf16x8 v;
  #pragma unroll
  for(int e=0;e<4;++e){ v[e] = (__bf16)f0[e]; v[4+e] = (__bf16)f1[e]; }
  *(bf16x8*)(out + (size_t)i*8) = v;
}

// ---------- 8-wave MFMA GEMV: out[16 b][16 j] for j-tile jt, K=1024 ----------
__device__ __forceinline__ void gemv_w8(const __bf16* __restrict__ hh,
                                        const __bf16* __restrict__ hl,
                                        const __bf16* __restrict__ Wp, int jt,
                                        float* __restrict__ out, int ldo,
                                        f32x4* red){
  int tid = threadIdx.x, lane = tid & 63, w = tid >> 6;
  const __bf16* Ah = hh + (lane&15)*1024 + (lane>>4)*8;
  const __bf16* Al = hl + (lane&15)*1024 + (lane>>4)*8;
  const __bf16* Bp = Wp + ((size_t)jt*32 + w*4)*1024 + lane*8;
  f32x4 acc = {0.f,0.f,0.f,0.f};
  #pragma unroll
  for(int kk=0;kk<4;++kk){
    int k0 = (w*4 + kk)*32;
    bf16x8 ah = *(const bf16x8*)(Ah + k0);
    bf16x8 al = *(const bf16x8*)(Al + k0);
    bf16x8 bh = *(const bf16x8*)(Bp + kk*1024);
    bf16x8 bl = *(const bf16x8*)(Bp + kk*1024 + 512);
    acc = MFMA16(ah, bh, acc, 0,0,0);
    acc = MFMA16(al, bh, acc, 0,0,0);
    acc = MFMA16(ah, bl, acc, 0,0,0);
  }
  red[w*64 + lane] = acc;
  __syncthreads();
  if(tid < 64){
    f32x4 s = red[tid];
    #pragma unroll
    for(int k=1;k<8;++k) s += red[k*64 + tid];
    int j = jt*16 + (tid & 15);
    #pragma unroll
    for(int i=0;i<4;++i) out[(size_t)((tid>>4)*4 + i)*ldo + j] = s[i];
  }
}

// ---------- boot: gh0(0) ----------
__global__ __launch_bounds__(512) void k_boot(const __bf16* __restrict__ hh,
                                              const __bf16* __restrict__ hl,
                                              const __bf16* __restrict__ Wp,
                                              float* __restrict__ gh0){
  __shared__ f32x4 red[512];
  gemv_w8(hh, hl, Wp, blockIdx.x, gh0, 3072, red);
}

// ---------- SA: gh1 (192 blk) ; q-slice + tanh-score partials (64 blk) ----------
__global__ __launch_bounds__(512) void k_SA(
    const __bf16* __restrict__ h1h, const __bf16* __restrict__ h1l,
    const __bf16* __restrict__ Whh1p, const __bf16* __restrict__ Wqp,
    const float* __restrict__ kp, const float* __restrict__ v_att,
    float* __restrict__ gh1, float* __restrict__ parts)
{
  __shared__ f32x4 red[512];
  __shared__ float qs[16][16];
  int blk = blockIdx.x, tid = threadIdx.x;
  if(blk < 192){ gemv_w8(h1h, h1l, Whh1p, blk, gh1, 3072, red); return; }
  int slice = blk - 192;   // a-tile 0..63
  // phase 1: q[16 b][16 a] via MFMA into LDS
  {
    int lane = tid & 63, w = tid >> 6;
    const __bf16* Ah = h1h + (lane&15)*1024 + (lane>>4)*8;
    const __bf16* Al = h1l + (lane&15)*1024 + (lane>>4)*8;
    const __bf16* Bp = Wqp + ((size_t)slice*32 + w*4)*1024 + lane*8;
    f32x4 acc = {0.f,0.f,0.f,0.f};
    #pragma unroll
    for(int kk=0;kk<4;++kk){
      int k0 = (w*4 + kk)*32;
      bf16x8 ah = *(const bf16x8*)(Ah + k0);
      bf16x8 al = *(const bf16x8*)(Al + k0);
      bf16x8 bh = *(const bf16x8*)(Bp + kk*1024);
      bf16x8 bl = *(const bf16x8*)(Bp + kk*1024 + 512);
      acc = MFMA16(ah, bh, acc, 0,0,0);
      acc = MFMA16(al, bh, acc, 0,0,0);
      acc = MFMA16(ah, bl, acc, 0,0,0);
    }
    red[w*64 + lane] = acc;
    __syncthreads();
    if(tid < 64){
      f32x4 s = red[tid];
      #pragma unroll
      for(int k=1;k<8;++k) s += red[k*64 + tid];
      #pragma unroll
      for(int i=0;i<4;++i) qs[(tid>>4)*4 + i][tid&15] = s[i];
    }
    __syncthreads();
  }
  // phase 2: partials for all 1024 (b,s) pairs over this 16-a slice
  const float* vp = v_att + slice*16;
  f32x4 v0 = ld4(vp), v1 = ld4(vp+4), v2 = ld4(vp+8), v3 = ld4(vp+12);
  #pragma unroll
  for(int r=0;r<2;++r){
    int pair = r*512 + tid;          // b*64 + s
    int b = pair >> 6;
    const float* kpr = kp + (size_t)pair*1024 + slice*16;
    f32x4 c0 = ld4(kpr), c1 = ld4(kpr+4), c2 = ld4(kpr+8), c3 = ld4(kpr+12);
    float acc = 0.f;
    #pragma unroll
    for(int e=0;e<4;++e){
      acc += v0[e]*tanhf(qs[b][e]     + c0[e]);
      acc += v1[e]*tanhf(qs[b][4+e]   + c1[e]);
      acc += v2[e]*tanhf(qs[b][8+e]   + c2[e]);
      acc += v3[e]*tanhf(qs[b][12+e]  + c3[e]);
    }
    parts[(size_t)slice*1024 + pair] = acc;
  }
}

// ---------- SB: scores(sum parts)+softmax + attn.EW + GRU0 -> h0n ----------
// 256 blocks x 512: jt = blk>>2 (16 j), bq = blk&3 (4 b); wave = s-slice of 8.
__global__ __launch_bounds__(512) void k_SB(int t,
    const float* __restrict__ parts, const float* __restrict__ EW,
    const float* __restrict__ GX0x, const float* __restrict__ gh0,
    const float* __restrict__ b_hh0,
    const float* __restrict__ h0_in, float* __restrict__ h0_out,
    __bf16* __restrict__ h0h, __bf16* __restrict__ h0l)
{
  __shared__ float ssum[256][2];
  __shared__ float sc[4][64];
  __shared__ float sden[4];
  __shared__ float part[8][4][16][3];
  int blk = blockIdx.x, tid = threadIdx.x;
  int jt = blk >> 2, bq = blk & 3;
  // 1) score = sum over 64 slices
  {
    int p = tid >> 1, hf = tid & 1;
    int pair = bq*256 + p;
    const float* pp = parts + (size_t)(hf*32)*1024 + pair;
    float s = 0.f;
    #pragma unroll
    for(int k=0;k<32;++k) s += pp[(size_t)k*1024];
    ssum[p][hf] = s;
  }
  __syncthreads();
  if(tid < 256) sc[tid>>6][tid&63] = expf(ssum[tid][0] + ssum[tid][1]);
  __syncthreads();
  if(tid < 4){
    float d = 0.f;
    #pragma unroll
    for(int s2=0;s2<64;++s2) d += sc[tid][s2];
    sden[tid] = d;
  }
  __syncthreads();
  // 2) attn.EW partials
  int lane = tid & 63, w = tid >> 6;
  int bl = lane >> 4, jl = lane & 15;
  int b = bq*4 + bl, col = jt*16 + jl;
  float a0=0.f, a1=0.f, a2=0.f;
  const float* ewp = EW + ((size_t)(b*64 + w*8))*3072 + col;
  #pragma unroll
  for(int si=0; si<8; ++si){
    float e = sc[bl][w*8 + si];
    const float* r2 = ewp + (size_t)si*3072;
    a0 += e*r2[0]; a1 += e*r2[1024]; a2 += e*r2[2048];
  }
  part[w][bl][jl][0]=a0; part[w][bl][jl][1]=a1; part[w][bl][jl][2]=a2;
  __syncthreads();
  // 3) GRU0 combine
  if(tid < 64){
    int bl2 = tid >> 4, jl2 = tid & 15;
    int b2 = bq*4 + bl2, j = jt*16 + jl2;
    float xr=0.f, xz=0.f, xn=0.f;
    #pragma unroll
    for(int k=0;k<8;++k){ xr+=part[k][bl2][jl2][0]; xz+=part[k][bl2][jl2][1]; xn+=part[k][bl2][jl2][2]; }
    float inv = 1.0f / sden[bl2];
    const float* gx = GX0x + ((size_t)t*16 + b2)*3072 + j;   // includes b_ih0
    const float* g0 = gh0 + (size_t)b2*3072 + j;
    float r = sigm(xr*inv + gx[0]    + g0[0]    + b_hh0[j]);
    float z = sigm(xz*inv + gx[1024] + g0[1024] + b_hh0[1024+j]);
    float n = tanhf(xn*inv + gx[2048] + r*(g0[2048] + b_hh0[2048+j]));
    float hnew = (1.f-z)*n + z*h0_in[b2*1024 + j];
    h0_out[b2*1024 + j] = hnew;
    split2(hnew, &h0h[b2*1024 + j], &h0l[b2*1024 + j]);
  }
}

// ---------- SC: h1n 3-gate (64 blk) ; gh0(t+1) (192 blk) ----------
__global__ __launch_bounds__(512) void k_SC(int t,
    const __bf16* __restrict__ h0h, const __bf16* __restrict__ h0l,
    const __bf16* __restrict__ Wih1p, const __bf16* __restrict__ Whh0p,
    const float* __restrict__ b_ih1, const float* __restrict__ b_hh1,
    const float* __restrict__ gh1,
    const float* __restrict__ h1_in, float* __restrict__ h1_out,
    __bf16* __restrict__ h1h, __bf16* __restrict__ h1l,
    __bf16* __restrict__ Hb, float* __restrict__ gh0)
{
  __shared__ f32x4 red[1536];   // 24 KB
  __shared__ float xg[3][16][16];
  int blk = blockIdx.x, tid = threadIdx.x;
  if(blk >= 64){ gemv_w8(h0h, h0l, Whh0p, blk-64, gh0, 3072, red); return; }
  int lane = tid & 63, w = tid >> 6;
  const __bf16* Ah = h0h + (lane&15)*1024 + (lane>>4)*8;
  const __bf16* Al = h0l + (lane&15)*1024 + (lane>>4)*8;
  #pragma unroll
  for(int g=0; g<3; ++g){
    const __bf16* Bp = Wih1p + ((size_t)(g*64 + blk)*32 + w*4)*1024 + lane*8;
    f32x4 acc = {0.f,0.f,0.f,0.f};
    #pragma unroll
    for(int kk=0;kk<4;++kk){
      int k0 = (w*4 + kk)*32;
      bf16x8 ah = *(const bf16x8*)(Ah + k0);
      bf16x8 al = *(const bf16x8*)(Al + k0);
      bf16x8 bh = *(const bf16x8*)(Bp + kk*1024);
      bf16x8 bl = *(const bf16x8*)(Bp + kk*1024 + 512);
      acc = MFMA16(ah, bh, acc, 0,0,0);
      acc = MFMA16(al, bh, acc, 0,0,0);
      acc = MFMA16(ah, bl, acc, 0,0,0);
    }
    red[g*512 + w*64 + lane] = acc;
  }
  __syncthreads();
  if(tid < 192){
    int g = tid >> 6, tt = tid & 63;
    f32x4 s = red[g*512 + tt];
    #pragma unroll
    for(int k=1;k<8;++k) s += red[g*512 + k*64 + tt];
    #pragma unroll
    for(int i=0;i<4;++i) xg[g][(tt>>4)*4 + i][tt&15] = s[i];
  }
  __syncthreads();
  if(tid < 256){
    int b = tid >> 4, jl = tid & 15, j = blk*16 + jl;
    float xr = xg[0][b][jl] + b_ih1[j];
    float xz = xg[1][b][jl] + b_ih1[1024+j];
    float xn = xg[2][b][jl] + b_ih1[2048+j];
    const float* g1 = gh1 + (size_t)b*3072 + j;
    float r = sigm(xr + g1[0]    + b_hh1[j]);
    float z = sigm(xz + g1[1024] + b_hh1[1024+j]);
    float n = tanhf(xn + r*(g1[2048] + b_hh1[2048+j]));
    float hnew = (1.f-z)*n + z*h1_in[b*1024 + j];
    h1_out[b*1024 + j] = hnew;
    split2(hnew, &h1h[b*1024 + j], &h1l[b*1024 + j]);
    Hb[((size_t)t*16 + b)*1024 + j] = (__bf16)hnew;
  }
}

// ---------- logits: BM=256, BN=128, 512 thr, bf16 B, XCD-chunked swizzle ----------
__global__ __launch_bounds__(512) void k_logits(
    const __bf16* __restrict__ Hb, const __bf16* __restrict__ Wb,
    const float* __restrict__ b_out, float* __restrict__ out)
{
  int c = blockIdx.x & 7, j = blockIdx.x >> 3;
  int x = j & 3, y = (j >> 2)*8 + c;
  if(y >= 250) return;
  int tm0 = x*256, tn0 = y*128;
  __shared__ __align__(16) __bf16 As[256][40];
  __shared__ __align__(16) __bf16 Bs[128][40];
  int tid = threadIdx.x;
  int lane = tid & 63, wave = tid >> 6;
  int wr = wave >> 1, wc = wave & 1;
  int qq = lane >> 4, rr = lane & 15;
  f32x4 acc[4][4] = {};
  int ar = tid >> 2, ak = (tid & 3) * 8;
  for(int k0=0;k0<1024;k0+=32){
    bf16x8 a0v = *(const bf16x8*)(Hb + (size_t)(tm0+ar)*1024     + k0 + ak);
    bf16x8 a1v = *(const bf16x8*)(Hb + (size_t)(tm0+ar+128)*1024 + k0 + ak);
    bf16x8 bv  = *(const bf16x8*)(Wb + (size_t)(tn0+ar)*1024     + k0 + ak);
    __syncthreads();
    *(bf16x8*)&As[ar][ak]     = a0v;
    *(bf16x8*)&As[ar+128][ak] = a1v;
    *(bf16x8*)&Bs[ar][ak]     = bv;
    __syncthreads();
    bf16x8 af[4], bfr[4];
    #pragma unroll
    for(int mi=0;mi<4;++mi) af[mi]  = *(const bf16x8*)&As[wr*64 + mi*16 + rr][qq*8];
    #pragma unroll
    for(int ni=0;ni<4;++ni) bfr[ni] = *(const bf16x8*)&Bs[wc*64 + ni*16 + rr][qq*8];
    #pragma unroll
    for(int mi=0;mi<4;++mi)
      #pragma unroll
      for(int ni=0;ni<4;++ni)
        acc[mi][ni] = MFMA16(af[mi], bfr[ni], acc[mi][ni], 0,0,0);
  }
  #pragma unroll
  for(int mi=0;mi<4;++mi)
    #pragma unroll
    for(int ni=0;ni<4;++ni)
      #pragma unroll
      for(int i=0;i<4;++i){
        int m = tm0 + wr*64 + mi*16 + qq*4 + i;
        int v = tn0 + wc*64 + ni*16 + rr;
        int bb = m & 15, tt = m >> 4;
        out[((size_t)bb*64 + tt)*32000 + v] = acc[mi][ni][i] + b_out[v];
      }
}

extern "C" void kernel_launch(void* const* d_in, const int* in_sizes, int n_in,
                              void* d_out, int out_size, void* d_ws, size_t ws_size,
                              hipStream_t stream){
  const int*   tgt    = (const int*)d_in[0];
  const float* hidden = (const float*)d_in[1];
  const float* enc    = (const float*)d_in[2];
  const float* emb    = (const float*)d_in[3];
  const float* Wq     = (const float*)d_in[4];
  const float* Wk     = (const float*)d_in[5];
  const float* v_att  = (const float*)d_in[6];
  const float* W_ih0  = (const float*)d_in[7];
  const float* W_hh0  = (const float*)d_in[8];
  const float* b_ih0  = (const float*)d_in[9];
  const float* b_hh0  = (const float*)d_in[10];
  const float* W_ih1  = (const float*)d_in[11];
  const float* W_hh1  = (const float*)d_in[12];
  const float* b_ih1  = (const float*)d_in[13];
  const float* b_hh1  = (const float*)d_in[14];
  const float* W_out  = (const float*)d_in[15];
  const float* b_out  = (const float*)d_in[16];
  float* out = (float*)d_out;

  float* ws = (float*)d_ws;
  size_t off = 0;
  auto alloc = [&](size_t n){ float* p = ws + off; off += n; return p; };
  float*  kp     = alloc((size_t)1024*1024);      // [b*64+s][a]
  float*  GX0x   = alloc((size_t)1024*3072);      // [t*16+b][3H] (+b_ih0)
  float*  EW     = alloc((size_t)1024*3072);      // [b*64+s][3H]
  __bf16* Whh0p  = (__bf16*)alloc((size_t)3072*1024);
  __bf16* Whh1p  = (__bf16*)alloc((size_t)3072*1024);
  __bf16* Wih1p  = (__bf16*)alloc((size_t)3072*1024);
  __bf16* Wqp    = (__bf16*)alloc((size_t)1024*1024);
  float*  gh0    = alloc((size_t)16*3072);
  float*  gh1    = alloc((size_t)16*3072);
  float*  parts  = alloc((size_t)64*1024);        // [slice][b*64+s]
  float*  h0A    = alloc((size_t)16*1024);
  float*  h0B    = alloc((size_t)16*1024);
  float*  h1A    = alloc((size_t)16*1024);
  float*  h1B    = alloc((size_t)16*1024);
  __bf16* h0sh   = (__bf16*)alloc((size_t)8192);
  __bf16* h0sl   = (__bf16*)alloc((size_t)8192);
  __bf16* h1sh   = (__bf16*)alloc((size_t)8192);
  __bf16* h1sl   = (__bf16*)alloc((size_t)8192);
  float*  Hb_f   = alloc((size_t)512*1024);
  __bf16* Hb     = (__bf16*)Hb_f;
  // aliases: emb_tok lives where Hb will go (dead before recurrence starts);
  // WT lives where EW will go (dead before EW GEMM); Woutb overlays the
  // kp..Wih1p region (all dead after the recurrence, before k_cvt16).
  float*  emb_tok = Hb_f;                 // 1024x512 fp32
  float*  WT      = EW;                   // 1024x1024 fp32 (Wk^T)
  __bf16* Woutb   = (__bf16*)ws;          // 32000x1024 bf16 = 16.384M floats
  (void)ws_size; (void)in_sizes; (void)n_in; (void)out_size;

  // ---- setup ----
  k_gather<<<1024,256,0,stream>>>(tgt, emb, emb_tok);
  k_transpose<<<dim3(32,32),256,0,stream>>>(Wk, WT, 1024, 1024);
  // kp = enc @ Wk
  k_gemm_s<<<dim3(8,16),256,0,stream>>>(enc,1024, WT,1024, nullptr, kp, 1024, 1024);
  // GX0x = emb_tok @ Wx^T + b_ih0  (Wx = W_ih0[:, :512])
  k_gemm_s<<<dim3(8,48),256,0,stream>>>(emb_tok,512, W_ih0,1536, b_ih0, GX0x, 3072, 512);
  // EW = enc @ Wc^T                (Wc = W_ih0[:, 512:1536]) — overwrites WT (dead)
  k_gemm_s<<<dim3(8,48),256,0,stream>>>(enc,1024, W_ih0+512,1536, nullptr, EW, 3072, 1024);
  // packed MFMA panels
  k_pack_wT<<<64,256,0,stream>>>(Wq, 1024, Wqp);        // Wq read transposed
  k_pack_w<<<192,256,0,stream>>>(W_hh0, Whh0p);
  k_pack_w<<<192,256,0,stream>>>(W_hh1, Whh1p);
  k_pack_w<<<192,256,0,stream>>>(W_ih1, Wih1p);
  k_split_h<<<128,256,0,stream>>>(hidden, h0sh, h0sl, h1sh, h1sl);
  k_boot<<<192,512,0,stream>>>(h0sh, h0sl, Whh0p, gh0);

  // ---- recurrence: 3 dispatches per step ----
  for(int t=0;t<64;++t){
    const float* h0i = (t==0)? hidden            : ((t&1)? h0A : h0B);
    float*       h0o = (t&1)? h0B : h0A;
    const float* h1i = (t==0)? hidden + 16*1024  : ((t&1)? h1A : h1B);
    float*       h1o = (t&1)? h1B : h1A;
    k_SA<<<256,512,0,stream>>>(h1sh, h1sl, Whh1p, Wqp, kp, v_att, gh1, parts);
    k_SB<<<256,512,0,stream>>>(t, parts, EW, GX0x, gh0, b_hh0, h0i, h0o, h0sh, h0sl);
    k_SC<<<256,512,0,stream>>>(t, h0sh, h0sl, Wih1p, Whh0p, b_ih1, b_hh1, gh1,
                               h1i, h1o, h1sh, h1sl, Hb, gh0);
  }

  // ---- deferred logits (W_out -> bf16 over dead panel region, then MFMA GEMM) ----
  k_cvt16<<<16000,256,0,stream>>>(W_out, Woutb);
  k_logits<<<1024,512,0,stream>>>(Hb, Woutb, b_out, out);
}